// Round 17
// baseline (499.151 us; speedup 1.0000x reference)
//
#include <hip/hip_runtime.h>

// ---------------------------------------------------------------------------
// RNN-T Joint Network, MI355X (gfx950)
//   f  = enc  @ W_enc^T   : [2048 x 640]
//   g  = pred @ W_pred^T  : [ 512 x 640]
//   out[b,t,u,v] = sum_j tanh(f[bt,j] + g[bu,j]) * W_out[v,j] + b_out[v]
// R17: 3 blocks/CU WITHOUT register caps (R10/R12 failure) and WITHOUT
// shrinking per-SIMD MFMA density (R11 failure):
//   BM=128, BN=256, BK=32, 512 thr = 8 waves, wave tile 64x64 -> acc 64 AGPR,
//   unified regs ~175 (no launch_bounds min-waves hint -> no forced spill),
//   LDS 48KB (A 2x8KB identity [R16: measured 0 conflicts], B 2x16KB
//   pre-tiled identity) -> 3 blocks/CU, 6 waves/SIMD, occupancy 75%.
//   Inter-block overlap (no shared barriers) fills in-loop stalls AND the
//   retirement store-drain (the two measured losses of the R9 structure).
// ---------------------------------------------------------------------------

typedef _Float16 f16x8 __attribute__((ext_vector_type(8)));
typedef float    f32x4 __attribute__((ext_vector_type(4)));

__device__ __forceinline__ float fast_tanh(float x) {
    float e = __builtin_amdgcn_exp2f(x * 2.88539008177792681472f);
    return 1.0f - 2.0f * __builtin_amdgcn_rcpf(e + 1.0f);
}

__device__ __forceinline__ void gll16(const void* g, void* l) {
    __builtin_amdgcn_global_load_lds(
        (const __attribute__((address_space(1))) void*)g,
        (__attribute__((address_space(3))) void*)l, 16, 0, 0);
}

// ---------------------------------------------------------------------------
// Kernel 1: fg GEMM (fp32, exact). W staged transposed -> broadcast reads.
// ---------------------------------------------------------------------------
__global__ __launch_bounds__(256) void fg_kernel(
    const float* __restrict__ enc, const float* __restrict__ pred,
    const float* __restrict__ Wenc, const float* __restrict__ Wpred,
    float* __restrict__ fg)
{
    __shared__ float As[64][36];
    __shared__ float WsT[32][68];

    const int bid = blockIdx.x;
    const int mt = bid / 10;
    const int nt = bid % 10;
    const int m0 = mt * 64;
    const int n0 = nt * 64;

    const float* Aptr;
    const float* Wptr;
    if (m0 < 2048) { Aptr = enc  + (size_t)m0 * 512;          Wptr = Wenc; }
    else           { Aptr = pred + (size_t)(m0 - 2048) * 512; Wptr = Wpred; }

    const int t  = threadIdx.x;
    const int ty = t >> 4;
    const int tx = t & 15;
    const int lr = t >> 2;
    const int lc = (t & 3) * 8;
    const int lane6 = t & 63;
    const int w8    = (t >> 6) * 8;

    float acc[4][4];
#pragma unroll
    for (int i = 0; i < 4; ++i)
#pragma unroll
        for (int j = 0; j < 4; ++j) acc[i][j] = 0.0f;

    for (int k0 = 0; k0 < 512; k0 += 32) {
        __syncthreads();
        {
            const float* sa = Aptr + (size_t)lr * 512 + k0 + lc;
            f32x4 a0 = *(const f32x4*)(sa);
            f32x4 a1 = *(const f32x4*)(sa + 4);
            *(f32x4*)&As[lr][lc]     = a0;
            *(f32x4*)&As[lr][lc + 4] = a1;
            const float* sw = Wptr + (size_t)(n0 + lane6) * 512 + k0 + w8;
            f32x4 w0 = *(const f32x4*)(sw);
            f32x4 w1 = *(const f32x4*)(sw + 4);
#pragma unroll
            for (int j = 0; j < 4; ++j) {
                WsT[w8 + j][lane6]     = w0[j];
                WsT[w8 + 4 + j][lane6] = w1[j];
            }
        }
        __syncthreads();
#pragma unroll
        for (int kk = 0; kk < 32; ++kk) {
            float av[4], bv[4];
#pragma unroll
            for (int i = 0; i < 4; ++i) av[i] = As[ty * 4 + i][kk];
#pragma unroll
            for (int j = 0; j < 4; ++j) bv[j] = WsT[kk][tx * 4 + j];
#pragma unroll
            for (int i = 0; i < 4; ++i)
#pragma unroll
                for (int j = 0; j < 4; ++j)
                    acc[i][j] = fmaf(av[i], bv[j], acc[i][j]);
        }
    }

#pragma unroll
    for (int i = 0; i < 4; ++i) {
        f32x4 v = { acc[i][0], acc[i][1], acc[i][2], acc[i][3] };
        *(f32x4*)&fg[(size_t)(m0 + ty * 4 + i) * 640 + n0 + tx * 4] = v;
    }
}

// ---------------------------------------------------------------------------
// Kernel 2: W_out fp32 [1024][640] -> fp16 tiled [seg][kc][L][8]:
// offset = seg*10240 + kc*512 + L*8, seg=n>>4, kc=k>>5, L=(n&15)+16*((k>>3)&3)
// -> 64-lane gll at base+lane*8 reads contiguous 1KB; slot L = what the MFMA
// B-fragment wants at lane L (identity, zero-conflict ds_read).
// ---------------------------------------------------------------------------
__global__ __launch_bounds__(256) void wconv_kernel(
    const float* __restrict__ W, _Float16* __restrict__ Wh)
{
    const int tid = blockIdx.x * 256 + threadIdx.x;    // 81920
    const int n   = tid / 80;
    const int c   = tid % 80;
    f32x4 a = *(const f32x4*)(W + (size_t)n * 640 + c * 8);
    f32x4 b = *(const f32x4*)(W + (size_t)n * 640 + c * 8 + 4);
    f16x8 h;
#pragma unroll
    for (int j = 0; j < 4; ++j) { h[j] = (_Float16)a[j]; h[4 + j] = (_Float16)b[j]; }
    const int seg = n >> 4;
    const int kc  = c >> 2;
    const int L   = (n & 15) + 16 * (c & 3);
    *(f16x8*)(Wh + (size_t)seg * 10240 + kc * 512 + L * 8) = h;
}

// ---------------------------------------------------------------------------
// Kernel 3: fused tanh + big GEMM.  BM=128, BN=256, BK=32, 512 thr = 8 waves
// (wm=wid&1: 64-row half; wn=wid>>1: 64-col quarter), wave tile 64x64
// (4x4 frags, 64 AGPR).  LDS 48KB -> 3 blocks/CU, 6 waves/SIMD.
// A identity (R16 mapping, measured 0 conflicts): thread t owns slot t:
//   row=(t>>6)*16+(t&15), kc8=(t>>4)&3; write at t*16B; read af[mf] =
//   Ash[(wm*4+mf)*512 + lane*8].  B: pre-tiled Wh, 16 segs; wave stages
//   segs wid*2,wid*2+1; read bf[nf] = Bsh[(wn*4+nf)*512 + lane*8].
// Per-iter: f/g loads(next) -> 2 gll B(next) -> frag reads(cur) ->
//   tanh(next, waits vmcnt(2)) -> 16 MFMA (setprio) -> ds_write A(next)
//   -> __syncthreads.
// ---------------------------------------------------------------------------
__global__ __launch_bounds__(512) void joint_kernel(
    const float* __restrict__ fg, const _Float16* __restrict__ Wh,
    const float* __restrict__ bias, float* __restrict__ out)
{
    __shared__ _Float16 Ash0[4096];        // 8 KB  (128 rows x 32 k)
    __shared__ _Float16 Ash1[4096];
    __shared__ _Float16 Bsh0[8192];        // 16 KB (256 rows x 32 k)
    __shared__ _Float16 Bsh1[8192];

    const int bid = blockIdx.x;            // 4096
    const int pp  = bid >> 2;              // 1024 m-tiles
    const int mt  = (pp & 7) * 128 + (pp >> 3);   // XCD-chunked (bijective)
    const int nt  = bid & 3;               // 4 n-tiles of 256
    const int m0  = mt << 7;

    const int t    = threadIdx.x;
    const int lane = t & 63;
    const int wid  = t >> 6;
    const int wm   = wid & 1;              // m half (64 rows)
    const int wn   = wid >> 1;             // n quarter (64 cols)
    const int lr   = lane & 15;
    const int lk   = lane >> 4;

    // stage-A identity mapping (R16, measured zero-conflict):
    const int arow = ((t >> 6) << 4) + (t & 15);   // 0..127
    const int akc8 = (t >> 4) & 3;                 // k-chunk of 8
    const int m    = m0 + arow;
    const float* grow = fg + (size_t)(2048 + ((m >> 14) << 6) + (m & 63)) * 640;
    const float* frow = fg + (size_t)(m >> 6) * 640;
    const int aw = t * 8;                  // A write offset (f16 elems)

    // ---- loop-invariant LDS offsets (f16 elems) ----
    int aoff[4];
#pragma unroll
    for (int mf = 0; mf < 4; ++mf)
        aoff[mf] = (wm * 4 + mf) * 512 + lane * 8;     // identity
    int boff[4];
#pragma unroll
    for (int nf = 0; nf < 4; ++nf)
        boff[nf] = (wn * 4 + nf) * 512 + lane * 8;     // identity

    // gll: wave stages B segs wid*2, wid*2+1 (1KB each, contiguous source)
    const _Float16* gbase = Wh + (size_t)(nt * 16 + wid * 2) * 10240 + lane * 8;
    const int gd0 = (wid * 2) * 512;
    const int gd1 = (wid * 2 + 1) * 512;

    f32x4 acc[4][4];
#pragma unroll
    for (int i = 0; i < 4; ++i)
#pragma unroll
        for (int j = 0; j < 4; ++j) acc[i][j] = (f32x4){0.f, 0.f, 0.f, 0.f};

    // ---- prologue: stage k-range 0 into Ash0/Bsh0 ----
    {
        f32x4 fv0 = *(const f32x4*)(frow + akc8 * 8);
        f32x4 fv1 = *(const f32x4*)(frow + akc8 * 8 + 4);
        f32x4 gv0 = *(const f32x4*)(grow + akc8 * 8);
        f32x4 gv1 = *(const f32x4*)(grow + akc8 * 8 + 4);
        gll16(gbase,         &Bsh0[gd0]);
        gll16(gbase + 10240, &Bsh0[gd1]);
        f16x8 h;
#pragma unroll
        for (int j = 0; j < 4; ++j) {
            h[j]     = (_Float16)fast_tanh(fv0[j] + gv0[j]);
            h[4 + j] = (_Float16)fast_tanh(fv1[j] + gv1[j]);
        }
        *(f16x8*)&Ash0[aw] = h;
        __syncthreads();
    }

#define JITER_FULL(K0, CA, CB, NA, NB)                                         \
    {                                                                          \
        const int kn_ = (K0) + 32;                                             \
        /* f/g loads FIRST: tanh waits vmcnt(2), glls stay in flight */        \
        f32x4 fv0_ = *(const f32x4*)(frow + kn_ + akc8 * 8);                   \
        f32x4 fv1_ = *(const f32x4*)(frow + kn_ + akc8 * 8 + 4);               \
        f32x4 gv0_ = *(const f32x4*)(grow + kn_ + akc8 * 8);                   \
        f32x4 gv1_ = *(const f32x4*)(grow + kn_ + akc8 * 8 + 4);               \
        gll16(gbase + kn_ * 16,         &NB[gd0]);                             \
        gll16(gbase + 10240 + kn_ * 16, &NB[gd1]);                             \
        f16x8 af[4], bf[4];                                                    \
        _Pragma("unroll")                                                      \
        for (int mf = 0; mf < 4; ++mf)                                         \
            af[mf] = *(const f16x8*)&CA[aoff[mf]];                             \
        _Pragma("unroll")                                                      \
        for (int nf = 0; nf < 4; ++nf)                                         \
            bf[nf] = *(const f16x8*)&CB[boff[nf]];                             \
        f16x8 h_;                                                              \
        _Pragma("unroll")                                                      \
        for (int j = 0; j < 4; ++j) {                                          \
            h_[j]     = (_Float16)fast_tanh(fv0_[j] + gv0_[j]);                \
            h_[4 + j] = (_Float16)fast_tanh(fv1_[j] + gv1_[j]);                \
        }                                                                      \
        __builtin_amdgcn_s_setprio(1);                                         \
        _Pragma("unroll")                                                      \
        for (int mf = 0; mf < 4; ++mf)                                         \
            _Pragma("unroll")                                                  \
            for (int nf = 0; nf < 4; ++nf)                                     \
                acc[mf][nf] = __builtin_amdgcn_mfma_f32_16x16x32_f16(          \
                    af[mf], bf[nf], acc[mf][nf], 0, 0, 0);                     \
        __builtin_amdgcn_s_setprio(0);                                         \
        *(f16x8*)&NA[aw] = h_;                                                 \
        __syncthreads();                                                       \
    }

#define JITER_LAST(CA, CB)                                                     \
    {                                                                          \
        f16x8 af[4], bf[4];                                                    \
        _Pragma("unroll")                                                      \
        for (int mf = 0; mf < 4; ++mf)                                         \
            af[mf] = *(const f16x8*)&CA[aoff[mf]];                             \
        _Pragma("unroll")                                                      \
        for (int nf = 0; nf < 4; ++nf)                                         \
            bf[nf] = *(const f16x8*)&CB[boff[nf]];                             \
        __builtin_amdgcn_s_setprio(1);                                         \
        _Pragma("unroll")                                                      \
        for (int mf = 0; mf < 4; ++mf)                                         \
            _Pragma("unroll")                                                  \
            for (int nf = 0; nf < 4; ++nf)                                     \
                acc[mf][nf] = __builtin_amdgcn_mfma_f32_16x16x32_f16(          \
                    af[mf], bf[nf], acc[mf][nf], 0, 0, 0);                     \
        __builtin_amdgcn_s_setprio(0);                                         \
    }

    for (int kc = 0; kc < 18; kc += 2) {
        JITER_FULL(kc * 32,      Ash0, Bsh0, Ash1, Bsh1);
        JITER_FULL(kc * 32 + 32, Ash1, Bsh1, Ash0, Bsh0);
    }
    JITER_FULL(576, Ash0, Bsh0, Ash1, Bsh1);   // computes k=576, stages 608
    JITER_LAST(Ash1, Bsh1);                    // computes k=608

#undef JITER_FULL
#undef JITER_LAST

    // ---- epilogue: + bias, cached fp32 stores ----
    float bv[4];
#pragma unroll
    for (int nf = 0; nf < 4; ++nf)
        bv[nf] = bias[nt * 256 + wn * 64 + nf * 16 + lr];

#pragma unroll
    for (int mf = 0; mf < 4; ++mf) {
#pragma unroll
        for (int rr = 0; rr < 4; ++rr) {
            const int row = m0 + wm * 64 + mf * 16 + lk * 4 + rr;
            float* orow = out + (size_t)row * 1024 + nt * 256 + wn * 64;
#pragma unroll
            for (int nf = 0; nf < 4; ++nf)
                orow[nf * 16 + lr] = acc[mf][nf][rr] + bv[nf];
        }
    }
}

// ---------------------------------------------------------------------------
extern "C" void kernel_launch(void* const* d_in, const int* in_sizes, int n_in,
                              void* d_out, int out_size, void* d_ws, size_t ws_size,
                              hipStream_t stream) {
    const float* enc   = (const float*)d_in[0];   // [8,256,512]
    const float* pred  = (const float*)d_in[1];   // [8,64,512]
    const float* Wenc  = (const float*)d_in[2];   // [640,512]
    const float* Wpred = (const float*)d_in[3];   // [640,512]
    const float* Wout  = (const float*)d_in[4];   // [1024,640]
    const float* bout  = (const float*)d_in[5];   // [1024]

    float*     fg = (float*)d_ws;                              // 2560*640 fp32
    _Float16*  Wh = (_Float16*)((char*)d_ws + 2560 * 640 * 4); // tiled 1.25MB

    fg_kernel<<<400, 256, 0, stream>>>(enc, pred, Wenc, Wpred, fg);
    wconv_kernel<<<320, 256, 0, stream>>>(Wout, Wh);
    joint_kernel<<<4096, 512, 0, stream>>>(fg, Wh, bout, (float*)d_out);
}